// Round 8
// baseline (212.646 us; speedup 1.0000x reference)
//
#include <hip/hip_runtime.h>
#include <math.h>

#define D128 128
#define ROWS 16
#define SCAP 1024   // LDS score-buffer capacity (deg ~ Poisson(32); P(deg>1024)~0)

typedef unsigned int uint32;
typedef unsigned short ushort_t;
typedef short bf16x8 __attribute__((ext_vector_type(8)));
typedef float f32x4 __attribute__((ext_vector_type(4)));

// fp32 -> bf16 (RNE)
__device__ __forceinline__ ushort_t bf16_of(float x) {
  uint32 u = __float_as_uint(x);
  return (ushort_t)((u + 0x7fffu + ((u >> 16) & 1u)) >> 16);
}
__device__ __forceinline__ uint32 pack_bf2(float x, float y) {
  uint32 bx = __float_as_uint(x);
  uint32 by = __float_as_uint(y);
  bx = (bx + 0x7fffu + ((bx >> 16) & 1u)) >> 16;
  by = (by + 0x7fffu + ((by >> 16) & 1u)) & 0xffff0000u;
  return bx | by;
}
__device__ __forceinline__ float bf_lo(uint32 u) { return __uint_as_float(u << 16); }
__device__ __forceinline__ float bf_hi(uint32 u) { return __uint_as_float(u & 0xffff0000u); }

// tanh(x) = 1 - 2/(1+exp(2x)) via v_exp + v_rcp
__device__ __forceinline__ float fast_tanh(float x) {
  float e = __expf(2.0f * x);
  float r = __builtin_amdgcn_rcpf(1.0f + e);
  return fmaf(-2.0f, r, 1.0f);
}

// ---------------------------------------------------------------------------
// prep_all: one dispatch, block-range partitioned:
//   [0, nb_conv)              : fp32->bf16 convert of h_src then s_emb
//   [nb_conv, +16)            : W1 -> MFMA-fragment-ordered bf16 Wfrag
//                               Wfrag[((h*8+nt)*4+kc)*64+lane][j] =
//                                 W1[h*128 + kc*32 + (lane>>4)*8 + j][nt*16 + (lane&15)]
//   [nb_conv+16, +64)         : Wo -> packed bf16 pairs Wo_p[k2*128+c] =
//                                 pack(Wo[2k2][c], Wo[2k2+1][c])
//   [nb_conv+80, ...)         : segment offsets from sorted dst_idx
// ---------------------------------------------------------------------------
__global__ __launch_bounds__(256) void prep_all(
    const float* __restrict__ h_src, const float* __restrict__ s_emb,
    const float* __restrict__ W1, const float* __restrict__ Wo,
    const int* __restrict__ dst_idx,
    uint32* __restrict__ h_src_bf, uint32* __restrict__ s_emb_bf,
    ushort_t* __restrict__ Wfrag, uint32* __restrict__ Wo_p,
    int* __restrict__ off,
    int n_src_el, int n_tot_el, int E, int N, int nb_conv) {
  const int b = blockIdx.x;
  const int tid = threadIdx.x;
  if (b < nb_conv) {
    int i = (b * 256 + tid) * 8;
    if (i >= n_tot_el) return;
    const float* src;
    uint32* dst;
    if (i < n_src_el) { src = h_src + i; dst = h_src_bf + (i >> 1); }
    else { src = s_emb + (i - n_src_el); dst = s_emb_bf + ((i - n_src_el) >> 1); }
    float4 a = *(const float4*)src;
    float4 c = *(const float4*)(src + 4);
    uint4 p;
    p.x = pack_bf2(a.x, a.y);
    p.y = pack_bf2(a.z, a.w);
    p.z = pack_bf2(c.x, c.y);
    p.w = pack_bf2(c.z, c.w);
    *(uint4*)dst = p;
  } else if (b < nb_conv + 16) {
    int t = (b - nb_conv) * 256 + tid;   // 0..4095 : one B-fragment (8 elems)
    int lane = t & 63;
    int kc = (t >> 6) & 3;
    int nt = (t >> 8) & 7;
    int h = (t >> 11) & 1;
    int m = lane & 15;
    int quad = lane >> 4;
    int krow = h * D128 + kc * 32 + quad * 8;
    int ncol = nt * 16 + m;
    ushort_t fr[8];
#pragma unroll
    for (int j = 0; j < 8; j++) fr[j] = bf16_of(W1[(size_t)(krow + j) * D128 + ncol]);
    *(uint4*)(Wfrag + (size_t)t * 8) = *(const uint4*)fr;
  } else if (b < nb_conv + 80) {
    int t = (b - nb_conv - 16) * 256 + tid;   // 0..16383
    int k2 = t >> 7;
    int c = t & 127;
    Wo_p[t] = pack_bf2(Wo[(size_t)(2 * k2) * D128 + c],
                       Wo[(size_t)(2 * k2 + 1) * D128 + c]);
  } else {
    int e = (b - nb_conv - 80) * 256 + tid;
    if (e >= E) return;
    int d = dst_idx[e];
    int dprev = (e == 0) ? -1 : dst_idx[e - 1];
    for (int v = dprev + 1; v <= d; v++) off[v] = e;
    if (e == E - 1) {
      for (int v = d + 1; v <= N; v++) off[v] = E;
    }
  }
}

// ---------------------------------------------------------------------------
// Merged GEMM: P = X @ W for two problems in one dispatch (bf16 MFMA).
// A: direct per-lane global loads (zero block reuse). B: fragment-ordered
// Wfrag -> each wave-load is ONE contiguous 1 KB segment, L2-hot.
// Epilogue: LDS repack -> coalesced 8-B stores.
// ---------------------------------------------------------------------------
__global__ __launch_bounds__(256) void gemm_mfma(
    const ushort_t* __restrict__ Xa, const ushort_t* __restrict__ Xb,
    const ushort_t* __restrict__ Wfrag,
    ushort_t* __restrict__ Pa, ushort_t* __restrict__ Pb,
    int Ma, int Mb, int nblk_a) {
  __shared__ ushort_t Ys[128][132];
  const int blk = blockIdx.x;
  const ushort_t* X;
  const bf16x8* Wf;
  ushort_t* P;
  int M, row0;
  if (blk < nblk_a) { X = Xa; P = Pa; Wf = (const bf16x8*)Wfrag;          M = Ma; row0 = blk * 128; }
  else              { X = Xb; P = Pb; Wf = (const bf16x8*)(Wfrag + 16384); M = Mb; row0 = (blk - nblk_a) * 128; }

  const int tid = threadIdx.x;
  const int wave = tid >> 6;
  const int lane = tid & 63;
  const int m = lane & 15;
  const int quad = lane >> 4;

  const int ra0 = min(row0 + wave * 32 + m, M - 1);
  const int ra1 = min(row0 + wave * 32 + 16 + m, M - 1);

  f32x4 acc[2][8];
#pragma unroll
  for (int st = 0; st < 2; st++)
#pragma unroll
    for (int nt = 0; nt < 8; nt++) acc[st][nt] = (f32x4){0.f, 0.f, 0.f, 0.f};

#pragma unroll
  for (int kc = 0; kc < 4; kc++) {
    bf16x8 a0 = *(const bf16x8*)(X + (size_t)ra0 * D128 + kc * 32 + quad * 8);
    bf16x8 a1 = *(const bf16x8*)(X + (size_t)ra1 * D128 + kc * 32 + quad * 8);
#pragma unroll
    for (int nt = 0; nt < 8; nt++) {
      bf16x8 bfr = Wf[(nt * 4 + kc) * 64 + lane];
      acc[0][nt] = __builtin_amdgcn_mfma_f32_16x16x32_bf16(a0, bfr, acc[0][nt], 0, 0, 0);
      acc[1][nt] = __builtin_amdgcn_mfma_f32_16x16x32_bf16(a1, bfr, acc[1][nt], 0, 0, 0);
    }
  }

#pragma unroll
  for (int st = 0; st < 2; st++)
#pragma unroll
    for (int nt = 0; nt < 8; nt++)
#pragma unroll
      for (int r = 0; r < 4; r++)
        Ys[wave * 32 + st * 16 + quad * 4 + r][nt * 16 + m] = bf16_of(acc[st][nt][r]);
  __syncthreads();

#pragma unroll
  for (int it = 0; it < 16; it++) {
    int f = tid + 256 * it;
    int row = f >> 5;
    int c = (f & 31) * 4;
    int grow = row0 + row;
    if (grow < M) {
      uint2 v = *(const uint2*)(&Ys[row][c]);
      *(uint2*)(P + (size_t)grow * D128 + c) = v;
    }
  }
}

// ---------------------------------------------------------------------------
// Fused attention + aggregation, one 256-thread block per dst.
// No seg-max pass: |raw| <= sum|w2| ~ 15, exp() is safe in fp32 and
// exp(raw)/sum(exp(raw)) == exp(raw-max)/sum(exp(raw-max)).
// ---------------------------------------------------------------------------
__global__ __launch_bounds__(256) void attn_agg_kernel(
    const uint32* __restrict__ p_src_bf, const uint32* __restrict__ p_dst_bf,
    const float* __restrict__ w2, const float* __restrict__ ew,
    const int* __restrict__ src_idx, const int* __restrict__ off,
    const uint32* __restrict__ h_src_bf2,
    float* __restrict__ attn_out, float* __restrict__ h_global) {
  const int v = blockIdx.x;
  const int tid = threadIdx.x;
  const int lo = off[v], hi = off[v + 1];
  const int deg = hi - lo;
  const int sub = tid & 15;
  const int eg16 = tid >> 4;
  const int t2 = tid & 63;
  const int wv = tid >> 6;

  __shared__ float sw2[128];
  __shared__ uint32 spd[64];
  __shared__ float sred[4];
  __shared__ float sex[SCAP];
  __shared__ int ssrc[SCAP];
  __shared__ float sacc[4][128];

  if (tid < 128) sw2[tid] = w2[tid];
  if (tid < 64) spd[tid] = p_dst_bf[(size_t)v * 64 + tid];
  __syncthreads();

  float accx = 0.f, accy = 0.f;
  float inv;

  if (deg <= SCAP) {
    // ---- fast path: everything in LDS ----
    for (int base = 0; base < deg; base += 16) {
      int ei = base + eg16;
      float acc = 0.f;
      int s = 0;
      if (ei < deg) {
        int e = lo + ei;
        s = src_idx[e];
        uint4 us = *(const uint4*)(p_src_bf + (size_t)s * 64 + sub * 4);
        uint4 ud = *(const uint4*)(&spd[sub * 4]);
        float4 wA = *(const float4*)(&sw2[sub * 8]);
        float4 wB = *(const float4*)(&sw2[sub * 8 + 4]);
        acc = fast_tanh(bf_lo(us.x) + bf_lo(ud.x)) * wA.x;
        acc = fmaf(fast_tanh(bf_hi(us.x) + bf_hi(ud.x)), wA.y, acc);
        acc = fmaf(fast_tanh(bf_lo(us.y) + bf_lo(ud.y)), wA.z, acc);
        acc = fmaf(fast_tanh(bf_hi(us.y) + bf_hi(ud.y)), wA.w, acc);
        acc = fmaf(fast_tanh(bf_lo(us.z) + bf_lo(ud.z)), wB.x, acc);
        acc = fmaf(fast_tanh(bf_hi(us.z) + bf_hi(ud.z)), wB.y, acc);
        acc = fmaf(fast_tanh(bf_lo(us.w) + bf_lo(ud.w)), wB.z, acc);
        acc = fmaf(fast_tanh(bf_hi(us.w) + bf_hi(ud.w)), wB.w, acc);
      }
#pragma unroll
      for (int o = 1; o <= 8; o <<= 1) acc += __shfl_xor(acc, o, 64);
      if (ei < deg && sub == 0) { sex[ei] = acc * ew[lo + ei]; ssrc[ei] = s; }
    }
    // pad to multiple of 8 for the batched aggregation (ex=0 contributes 0)
    const int pad = (deg + 7) & ~7;
    for (int i = deg + tid; i < pad; i += 256) { sex[i] = 0.f; ssrc[i] = 0; }
    __syncthreads();

    // exp + den (sex[i] -> exp value), each i touched by exactly one thread
    float dp = 0.f;
    for (int i = tid; i < deg; i += 256) {
      float ex = __expf(sex[i]);
      sex[i] = ex;
      dp += ex;
    }
#pragma unroll
    for (int o = 32; o >= 1; o >>= 1) dp += __shfl_xor(dp, o, 64);
    if (t2 == 0) sred[wv] = dp;
    __syncthreads();
    inv = (deg > 0) ? 1.0f / (((sred[0] + sred[1]) + (sred[2] + sred[3]))) : 0.0f;

    // contiguous normalized attn store
    for (int i = tid; i < deg; i += 256) attn_out[lo + i] = sex[i] * inv;

    // aggregation: 8 gathers in flight per wave
    const int nb = (deg + 7) >> 3;
    for (int b = wv; b < nb; b += 4) {
      const int base = b * 8;
#pragma unroll
      for (int j = 0; j < 8; j++) {
        float ex = sex[base + j];
        int s = ssrc[base + j];
        uint32 u = h_src_bf2[(size_t)s * 64 + t2];
        accx = fmaf(ex, bf_lo(u), accx);
        accy = fmaf(ex, bf_hi(u), accy);
      }
    }
  } else {
    // ---- slow path (deg > SCAP): raw scores staged via attn_out global ----
    for (int base = 0; base < deg; base += 16) {
      int ei = base + eg16;
      float acc = 0.f;
      if (ei < deg) {
        int e = lo + ei;
        int s = src_idx[e];
        uint4 us = *(const uint4*)(p_src_bf + (size_t)s * 64 + sub * 4);
        uint4 ud = *(const uint4*)(&spd[sub * 4]);
        float4 wA = *(const float4*)(&sw2[sub * 8]);
        float4 wB = *(const float4*)(&sw2[sub * 8 + 4]);
        acc = fast_tanh(bf_lo(us.x) + bf_lo(ud.x)) * wA.x;
        acc = fmaf(fast_tanh(bf_hi(us.x) + bf_hi(ud.x)), wA.y, acc);
        acc = fmaf(fast_tanh(bf_lo(us.y) + bf_lo(ud.y)), wA.z, acc);
        acc = fmaf(fast_tanh(bf_hi(us.y) + bf_hi(ud.y)), wA.w, acc);
        acc = fmaf(fast_tanh(bf_lo(us.z) + bf_lo(ud.z)), wB.x, acc);
        acc = fmaf(fast_tanh(bf_hi(us.z) + bf_hi(ud.z)), wB.y, acc);
        acc = fmaf(fast_tanh(bf_lo(us.w) + bf_lo(ud.w)), wB.z, acc);
        acc = fmaf(fast_tanh(bf_hi(us.w) + bf_hi(ud.w)), wB.w, acc);
      }
#pragma unroll
      for (int o = 1; o <= 8; o <<= 1) acc += __shfl_xor(acc, o, 64);
      if (ei < deg && sub == 0) attn_out[lo + ei] = acc * ew[lo + ei];
    }
    __syncthreads();

    float dp = 0.f;
    for (int i = tid; i < deg; i += 256) dp += __expf(attn_out[lo + i]);
#pragma unroll
    for (int o = 32; o >= 1; o >>= 1) dp += __shfl_xor(dp, o, 64);
    if (t2 == 0) sred[wv] = dp;
    __syncthreads();
    inv = 1.0f / (((sred[0] + sred[1]) + (sred[2] + sred[3])));

    for (int w0 = 0; w0 < deg; w0 += SCAP) {
      const int wn = min(SCAP, deg - w0);
      __syncthreads();
      for (int i = tid; i < wn; i += 256) {
        float ex = __expf(attn_out[lo + w0 + i]);
        sex[i] = ex;
        ssrc[i] = src_idx[lo + w0 + i];
        attn_out[lo + w0 + i] = ex * inv;
      }
      const int padw = (wn + 7) & ~7;
      for (int i = wn + tid; i < padw; i += 256) { sex[i] = 0.f; ssrc[i] = 0; }
      __syncthreads();
      const int nb = (wn + 7) >> 3;
      for (int b = wv; b < nb; b += 4) {
        const int base = b * 8;
#pragma unroll
        for (int j = 0; j < 8; j++) {
          float ex = sex[base + j];
          int s = ssrc[base + j];
          uint32 u = h_src_bf2[(size_t)s * 64 + t2];
          accx = fmaf(ex, bf_lo(u), accx);
          accy = fmaf(ex, bf_hi(u), accy);
        }
      }
    }
  }

  // cross-wave reduce + h_global store
  sacc[wv][t2 * 2] = accx;
  sacc[wv][t2 * 2 + 1] = accy;
  __syncthreads();
  if (tid < 128) {
    float s = (sacc[0][tid] + sacc[1][tid]) + (sacc[2][tid] + sacc[3][tid]);
    h_global[(size_t)v * D128 + tid] = s * inv;
  }
}

// ---------------------------------------------------------------------------
// out = [h_dst|h_global] @ Wo + bo; x = h_dst + out; y = LN(x)*gamma+beta
// 16 rows/block; Wo as packed bf16 pairs (Wo_p, 64 KB total, L2-hot).
// ---------------------------------------------------------------------------
__global__ __launch_bounds__(128) void out_ln_kernel(
    const float* __restrict__ h_dst, const float* __restrict__ h_global,
    const uint32* __restrict__ Wo_p, const float* __restrict__ bo,
    const float* __restrict__ gamma, const float* __restrict__ beta,
    float* __restrict__ y, int N) {
  const int t = threadIdx.x;
  const int v0 = blockIdx.x * ROWS;
  __shared__ float xs[ROWS][260];
  __shared__ float redbuf[ROWS][2][2];

#pragma unroll
  for (int r = 0; r < ROWS; r++) {
    int v = v0 + r;
    float hd = 0.f, hg = 0.f;
    if (v < N) {
      hd = h_dst[(size_t)v * D128 + t];
      hg = h_global[(size_t)v * D128 + t];
    }
    xs[r][t] = hd;
    xs[r][128 + t] = hg;
  }
  __syncthreads();

  float o[ROWS];
#pragma unroll
  for (int r = 0; r < ROWS; r++) o[r] = bo[t];

  for (int k2 = 0; k2 < 128; k2 += 2) {   // 2 packed pairs = 4 k per iter
    uint32 u0 = Wo_p[(size_t)k2 * D128 + t];
    uint32 u1 = Wo_p[(size_t)(k2 + 1) * D128 + t];
    float w0 = bf_lo(u0), w1 = bf_hi(u0);
    float w2_ = bf_lo(u1), w3 = bf_hi(u1);
#pragma unroll
    for (int r = 0; r < ROWS; r++) {
      float4 xv = *(const float4*)(&xs[r][k2 * 2]);
      o[r] = fmaf(xv.x, w0, o[r]);
      o[r] = fmaf(xv.y, w1, o[r]);
      o[r] = fmaf(xv.z, w2_, o[r]);
      o[r] = fmaf(xv.w, w3, o[r]);
    }
  }

  const int lane = t & 63;
  const int wv = t >> 6;
  float xr[ROWS];
#pragma unroll
  for (int r = 0; r < ROWS; r++) {
    float x = xs[r][t] + o[r];
    xr[r] = x;
    float s1 = x, s2 = x * x;
#pragma unroll
    for (int off = 32; off >= 1; off >>= 1) {
      s1 += __shfl_xor(s1, off, 64);
      s2 += __shfl_xor(s2, off, 64);
    }
    if (lane == 0) { redbuf[r][wv][0] = s1; redbuf[r][wv][1] = s2; }
  }
  __syncthreads();

#pragma unroll
  for (int r = 0; r < ROWS; r++) {
    int v = v0 + r;
    if (v >= N) continue;
    float S1 = redbuf[r][0][0] + redbuf[r][1][0];
    float S2 = redbuf[r][0][1] + redbuf[r][1][1];
    float mu = S1 * (1.0f / 128.0f);
    float var = S2 * (1.0f / 128.0f) - mu * mu;
    float out = (xr[r] - mu) / sqrtf(var + 1e-5f) * gamma[t] + beta[t];
    y[(size_t)v * D128 + t] = out;
  }
}

extern "C" void kernel_launch(void* const* d_in, const int* in_sizes, int n_in,
                              void* d_out, int out_size, void* d_ws, size_t ws_size,
                              hipStream_t stream) {
  const float* h_src = (const float*)d_in[0];
  const float* h_dst = (const float*)d_in[1];
  const float* s_emb = (const float*)d_in[2];
  const float* ew    = (const float*)d_in[3];
  const int* src_idx = (const int*)d_in[4];
  const int* dst_idx = (const int*)d_in[5];
  const float* W1    = (const float*)d_in[6];
  const float* w2    = (const float*)d_in[7];
  const float* Wo    = (const float*)d_in[8];
  const float* bo    = (const float*)d_in[9];
  const float* gamma = (const float*)d_in[10];
  const float* beta  = (const float*)d_in[11];

  const int N_src = in_sizes[0] / D128;
  const int N_dst = in_sizes[1] / D128;
  const int E = in_sizes[3];

  float* out_y = (float*)d_out;                       // [N_dst*128]
  float* out_attn = out_y + (size_t)N_dst * D128;     // [E]

  // ws layout (uints hold 2 bf16):
  uint32* p_src_bf = (uint32*)d_ws;                           // N_src*64
  uint32* p_dst_bf = p_src_bf + (size_t)N_src * 64;           // N_dst*64
  uint32* h_src_bf = p_dst_bf + (size_t)N_dst * 64;           // N_src*64
  float* h_glob = (float*)(h_src_bf + (size_t)N_src * 64);    // N_dst*128
  // s_emb_bf aliases h_glob: consumed by gemm BEFORE attn_agg writes h_glob
  uint32* s_emb_bf = (uint32*)h_glob;                         // N_dst*64
  int* seg_off = (int*)(h_glob + (size_t)N_dst * D128);       // N_dst+1
  ushort_t* Wfrag = (ushort_t*)(seg_off + N_dst + 1 + 3);     // 2*16384 shorts
  uint32* Wo_p = (uint32*)(Wfrag + 2 * 16384);                // 16384 uints

  const int n_src_el = N_src * D128;
  const int n_tot_el = (N_src + N_dst) * D128;
  const int nblk_a = (N_src + 127) / 128;
  const int nblk_b = (N_dst + 127) / 128;
  const int nb_conv = (n_tot_el / 8 + 255) / 256;
  const int nb_seg = (E + 255) / 256;

  prep_all<<<nb_conv + 80 + nb_seg, 256, 0, stream>>>(
      h_src, s_emb, W1, Wo, dst_idx, h_src_bf, s_emb_bf, Wfrag, Wo_p, seg_off,
      n_src_el, n_tot_el, E, N_dst, nb_conv);
  gemm_mfma<<<nblk_a + nblk_b, 256, 0, stream>>>(
      (const ushort_t*)h_src_bf, (const ushort_t*)s_emb_bf, Wfrag,
      (ushort_t*)p_src_bf, (ushort_t*)p_dst_bf, N_src, N_dst, nblk_a);
  attn_agg_kernel<<<N_dst, 256, 0, stream>>>(
      p_src_bf, p_dst_bf, w2, ew, src_idx, seg_off, h_src_bf, out_attn, h_glob);
  out_ln_kernel<<<(N_dst + ROWS - 1) / ROWS, 128, 0, stream>>>(
      h_dst, h_glob, Wo_p, bo, gamma, beta, out_y, N_dst);
}

// Round 9
// 177.356 us; speedup vs baseline: 1.1990x; 1.1990x over previous
//
#include <hip/hip_runtime.h>
#include <math.h>

#define D128 128
#define SCAP 1024   // LDS score-buffer capacity (deg ~ Poisson(32); P(deg>1024)~0)

typedef unsigned int uint32;
typedef unsigned short ushort_t;
typedef short bf16x8 __attribute__((ext_vector_type(8)));
typedef float f32x4 __attribute__((ext_vector_type(4)));

// fp32 -> bf16 (RNE)
__device__ __forceinline__ ushort_t bf16_of(float x) {
  uint32 u = __float_as_uint(x);
  return (ushort_t)((u + 0x7fffu + ((u >> 16) & 1u)) >> 16);
}
__device__ __forceinline__ uint32 pack_bf2(float x, float y) {
  uint32 bx = __float_as_uint(x);
  uint32 by = __float_as_uint(y);
  bx = (bx + 0x7fffu + ((bx >> 16) & 1u)) >> 16;
  by = (by + 0x7fffu + ((by >> 16) & 1u)) & 0xffff0000u;
  return bx | by;
}
__device__ __forceinline__ float bf_lo(uint32 u) { return __uint_as_float(u << 16); }
__device__ __forceinline__ float bf_hi(uint32 u) { return __uint_as_float(u & 0xffff0000u); }

// tanh(x) = 1 - 2/(1+exp(2x)) via v_exp + v_rcp
__device__ __forceinline__ float fast_tanh(float x) {
  float e = __expf(2.0f * x);
  float r = __builtin_amdgcn_rcpf(1.0f + e);
  return fmaf(-2.0f, r, 1.0f);
}

// ---------------------------------------------------------------------------
// prep_all: one dispatch, block-range partitioned:
//   [0, nb_conv)       : fp32->bf16 convert of h_src, s_emb, h_dst (streaming)
//   [nb_conv, +16)     : W1 -> MFMA-fragment-ordered bf16 Wfrag (K=128 x2)
//   [+16, +16)         : Wo -> MFMA-fragment-ordered bf16 Wo_frag (K=256)
//   [+32, ...)         : segment offsets from sorted dst_idx
// ---------------------------------------------------------------------------
__global__ __launch_bounds__(256) void prep_all(
    const float* __restrict__ h_src, const float* __restrict__ s_emb,
    const float* __restrict__ h_dst,
    const float* __restrict__ W1, const float* __restrict__ Wo,
    const int* __restrict__ dst_idx,
    uint32* __restrict__ h_src_bf, uint32* __restrict__ s_emb_bf,
    uint32* __restrict__ h_dst_bf,
    ushort_t* __restrict__ Wfrag, ushort_t* __restrict__ Wo_frag,
    int* __restrict__ off,
    int n_src_el, int n_dst_el, int E, int N, int nb_conv) {
  const int b = blockIdx.x;
  const int tid = threadIdx.x;
  if (b < nb_conv) {
    int i = (b * 256 + tid) * 8;
    const int n_tot_el = n_src_el + 2 * n_dst_el;
    if (i >= n_tot_el) return;
    const float* src;
    uint32* dst;
    if (i < n_src_el) { src = h_src + i; dst = h_src_bf + (i >> 1); }
    else if (i < n_src_el + n_dst_el) {
      src = s_emb + (i - n_src_el); dst = s_emb_bf + ((i - n_src_el) >> 1);
    } else {
      src = h_dst + (i - n_src_el - n_dst_el);
      dst = h_dst_bf + ((i - n_src_el - n_dst_el) >> 1);
    }
    float4 a = *(const float4*)src;
    float4 c = *(const float4*)(src + 4);
    uint4 p;
    p.x = pack_bf2(a.x, a.y);
    p.y = pack_bf2(a.z, a.w);
    p.z = pack_bf2(c.x, c.y);
    p.w = pack_bf2(c.z, c.w);
    *(uint4*)dst = p;
  } else if (b < nb_conv + 16) {
    // W1 fragments: t indexes [h][nt][kc][lane]
    int t = (b - nb_conv) * 256 + tid;   // 0..4095
    int lane = t & 63;
    int kc = (t >> 6) & 3;
    int nt = (t >> 8) & 7;
    int h = (t >> 11) & 1;
    int m = lane & 15;
    int quad = lane >> 4;
    int krow = h * D128 + kc * 32 + quad * 8;
    int ncol = nt * 16 + m;
    ushort_t fr[8];
#pragma unroll
    for (int j = 0; j < 8; j++) fr[j] = bf16_of(W1[(size_t)(krow + j) * D128 + ncol]);
    *(uint4*)(Wfrag + (size_t)t * 8) = *(const uint4*)fr;
  } else if (b < nb_conv + 32) {
    // Wo fragments: t indexes [nt][kc8][lane], kc8 in 0..7 (K=256)
    int t = (b - nb_conv - 16) * 256 + tid;   // 0..4095
    int lane = t & 63;
    int kc = (t >> 6) & 7;
    int nt = (t >> 9) & 7;
    int m = lane & 15;
    int quad = lane >> 4;
    int krow = kc * 32 + quad * 8;
    int ncol = nt * 16 + m;
    ushort_t fr[8];
#pragma unroll
    for (int j = 0; j < 8; j++) fr[j] = bf16_of(Wo[(size_t)(krow + j) * D128 + ncol]);
    *(uint4*)(Wo_frag + (size_t)t * 8) = *(const uint4*)fr;
  } else {
    int e = (b - nb_conv - 32) * 256 + tid;
    if (e >= E) return;
    int d = dst_idx[e];
    int dprev = (e == 0) ? -1 : dst_idx[e - 1];
    for (int v = dprev + 1; v <= d; v++) off[v] = e;
    if (e == E - 1) {
      for (int v = d + 1; v <= N; v++) off[v] = E;
    }
  }
}

// ---------------------------------------------------------------------------
// Merged GEMM: P = X @ W for two problems in one dispatch (bf16 MFMA).
// A: direct per-lane global loads. B: fragment-ordered Wfrag (1 KB wave-loads,
// L2-hot). Epilogue: LDS repack -> coalesced 8-B stores.
// ---------------------------------------------------------------------------
__global__ __launch_bounds__(256) void gemm_mfma(
    const ushort_t* __restrict__ Xa, const ushort_t* __restrict__ Xb,
    const ushort_t* __restrict__ Wfrag,
    ushort_t* __restrict__ Pa, ushort_t* __restrict__ Pb,
    int Ma, int Mb, int nblk_a) {
  __shared__ ushort_t Ys[128][132];
  const int blk = blockIdx.x;
  const ushort_t* X;
  const bf16x8* Wf;
  ushort_t* P;
  int M, row0;
  if (blk < nblk_a) { X = Xa; P = Pa; Wf = (const bf16x8*)Wfrag;           M = Ma; row0 = blk * 128; }
  else              { X = Xb; P = Pb; Wf = (const bf16x8*)(Wfrag + 16384); M = Mb; row0 = (blk - nblk_a) * 128; }

  const int tid = threadIdx.x;
  const int wave = tid >> 6;
  const int lane = tid & 63;
  const int m = lane & 15;
  const int quad = lane >> 4;

  const int ra0 = min(row0 + wave * 32 + m, M - 1);
  const int ra1 = min(row0 + wave * 32 + 16 + m, M - 1);

  f32x4 acc[2][8];
#pragma unroll
  for (int st = 0; st < 2; st++)
#pragma unroll
    for (int nt = 0; nt < 8; nt++) acc[st][nt] = (f32x4){0.f, 0.f, 0.f, 0.f};

#pragma unroll
  for (int kc = 0; kc < 4; kc++) {
    bf16x8 a0 = *(const bf16x8*)(X + (size_t)ra0 * D128 + kc * 32 + quad * 8);
    bf16x8 a1 = *(const bf16x8*)(X + (size_t)ra1 * D128 + kc * 32 + quad * 8);
#pragma unroll
    for (int nt = 0; nt < 8; nt++) {
      bf16x8 bfr = Wf[(nt * 4 + kc) * 64 + lane];
      acc[0][nt] = __builtin_amdgcn_mfma_f32_16x16x32_bf16(a0, bfr, acc[0][nt], 0, 0, 0);
      acc[1][nt] = __builtin_amdgcn_mfma_f32_16x16x32_bf16(a1, bfr, acc[1][nt], 0, 0, 0);
    }
  }

#pragma unroll
  for (int st = 0; st < 2; st++)
#pragma unroll
    for (int nt = 0; nt < 8; nt++)
#pragma unroll
      for (int r = 0; r < 4; r++)
        Ys[wave * 32 + st * 16 + quad * 4 + r][nt * 16 + m] = bf16_of(acc[st][nt][r]);
  __syncthreads();

#pragma unroll
  for (int it = 0; it < 16; it++) {
    int f = tid + 256 * it;
    int row = f >> 5;
    int c = (f & 31) * 4;
    int grow = row0 + row;
    if (grow < M) {
      uint2 v = *(const uint2*)(&Ys[row][c]);
      *(uint2*)(P + (size_t)grow * D128 + c) = v;
    }
  }
}

// ---------------------------------------------------------------------------
// Fused attention + aggregation, one 256-thread block per dst.
// No seg-max pass (|raw| <= sum|w2|, fp32 exp safe; softmax invariant).
// h_global emitted as bf16 pairs for the MFMA output projection.
// ---------------------------------------------------------------------------
__global__ __launch_bounds__(256) void attn_agg_kernel(
    const uint32* __restrict__ p_src_bf, const uint32* __restrict__ p_dst_bf,
    const float* __restrict__ w2, const float* __restrict__ ew,
    const int* __restrict__ src_idx, const int* __restrict__ off,
    const uint32* __restrict__ h_src_bf2,
    float* __restrict__ attn_out, uint32* __restrict__ h_glob_bf) {
  const int v = blockIdx.x;
  const int tid = threadIdx.x;
  const int lo = off[v], hi = off[v + 1];
  const int deg = hi - lo;
  const int sub = tid & 15;
  const int eg16 = tid >> 4;
  const int t2 = tid & 63;
  const int wv = tid >> 6;

  __shared__ float sw2[128];
  __shared__ uint32 spd[64];
  __shared__ float sred[4];
  __shared__ float sex[SCAP];
  __shared__ int ssrc[SCAP];
  __shared__ float sacc[4][128];

  if (tid < 128) sw2[tid] = w2[tid];
  if (tid < 64) spd[tid] = p_dst_bf[(size_t)v * 64 + tid];
  __syncthreads();

  float accx = 0.f, accy = 0.f;
  float inv;

  if (deg <= SCAP) {
    // ---- fast path: everything in LDS ----
    for (int base = 0; base < deg; base += 16) {
      int ei = base + eg16;
      float acc = 0.f;
      int s = 0;
      if (ei < deg) {
        int e = lo + ei;
        s = src_idx[e];
        uint4 us = *(const uint4*)(p_src_bf + (size_t)s * 64 + sub * 4);
        uint4 ud = *(const uint4*)(&spd[sub * 4]);
        float4 wA = *(const float4*)(&sw2[sub * 8]);
        float4 wB = *(const float4*)(&sw2[sub * 8 + 4]);
        acc = fast_tanh(bf_lo(us.x) + bf_lo(ud.x)) * wA.x;
        acc = fmaf(fast_tanh(bf_hi(us.x) + bf_hi(ud.x)), wA.y, acc);
        acc = fmaf(fast_tanh(bf_lo(us.y) + bf_lo(ud.y)), wA.z, acc);
        acc = fmaf(fast_tanh(bf_hi(us.y) + bf_hi(ud.y)), wA.w, acc);
        acc = fmaf(fast_tanh(bf_lo(us.z) + bf_lo(ud.z)), wB.x, acc);
        acc = fmaf(fast_tanh(bf_hi(us.z) + bf_hi(ud.z)), wB.y, acc);
        acc = fmaf(fast_tanh(bf_lo(us.w) + bf_lo(ud.w)), wB.z, acc);
        acc = fmaf(fast_tanh(bf_hi(us.w) + bf_hi(ud.w)), wB.w, acc);
      }
#pragma unroll
      for (int o = 1; o <= 8; o <<= 1) acc += __shfl_xor(acc, o, 64);
      if (ei < deg && sub == 0) { sex[ei] = acc * ew[lo + ei]; ssrc[ei] = s; }
    }
    const int pad = (deg + 7) & ~7;
    for (int i = deg + tid; i < pad; i += 256) { sex[i] = 0.f; ssrc[i] = 0; }
    __syncthreads();

    float dp = 0.f;
    for (int i = tid; i < deg; i += 256) {
      float ex = __expf(sex[i]);
      sex[i] = ex;
      dp += ex;
    }
#pragma unroll
    for (int o = 32; o >= 1; o >>= 1) dp += __shfl_xor(dp, o, 64);
    if (t2 == 0) sred[wv] = dp;
    __syncthreads();
    inv = (deg > 0) ? 1.0f / (((sred[0] + sred[1]) + (sred[2] + sred[3]))) : 0.0f;

    for (int i = tid; i < deg; i += 256) attn_out[lo + i] = sex[i] * inv;

    const int nb = (deg + 7) >> 3;
    for (int b = wv; b < nb; b += 4) {
      const int base = b * 8;
#pragma unroll
      for (int j = 0; j < 8; j++) {
        float ex = sex[base + j];
        int s = ssrc[base + j];
        uint32 u = h_src_bf2[(size_t)s * 64 + t2];
        accx = fmaf(ex, bf_lo(u), accx);
        accy = fmaf(ex, bf_hi(u), accy);
      }
    }
  } else {
    // ---- slow path (deg > SCAP): raw scores staged via attn_out global ----
    for (int base = 0; base < deg; base += 16) {
      int ei = base + eg16;
      float acc = 0.f;
      if (ei < deg) {
        int e = lo + ei;
        int s = src_idx[e];
        uint4 us = *(const uint4*)(p_src_bf + (size_t)s * 64 + sub * 4);
        uint4 ud = *(const uint4*)(&spd[sub * 4]);
        float4 wA = *(const float4*)(&sw2[sub * 8]);
        float4 wB = *(const float4*)(&sw2[sub * 8 + 4]);
        acc = fast_tanh(bf_lo(us.x) + bf_lo(ud.x)) * wA.x;
        acc = fmaf(fast_tanh(bf_hi(us.x) + bf_hi(ud.x)), wA.y, acc);
        acc = fmaf(fast_tanh(bf_lo(us.y) + bf_lo(ud.y)), wA.z, acc);
        acc = fmaf(fast_tanh(bf_hi(us.y) + bf_hi(ud.y)), wA.w, acc);
        acc = fmaf(fast_tanh(bf_lo(us.z) + bf_lo(ud.z)), wB.x, acc);
        acc = fmaf(fast_tanh(bf_hi(us.z) + bf_hi(ud.z)), wB.y, acc);
        acc = fmaf(fast_tanh(bf_lo(us.w) + bf_lo(ud.w)), wB.z, acc);
        acc = fmaf(fast_tanh(bf_hi(us.w) + bf_hi(ud.w)), wB.w, acc);
      }
#pragma unroll
      for (int o = 1; o <= 8; o <<= 1) acc += __shfl_xor(acc, o, 64);
      if (ei < deg && sub == 0) attn_out[lo + ei] = acc * ew[lo + ei];
    }
    __syncthreads();

    float dp = 0.f;
    for (int i = tid; i < deg; i += 256) dp += __expf(attn_out[lo + i]);
#pragma unroll
    for (int o = 32; o >= 1; o >>= 1) dp += __shfl_xor(dp, o, 64);
    if (t2 == 0) sred[wv] = dp;
    __syncthreads();
    inv = 1.0f / (((sred[0] + sred[1]) + (sred[2] + sred[3])));

    for (int w0 = 0; w0 < deg; w0 += SCAP) {
      const int wn = min(SCAP, deg - w0);
      __syncthreads();
      for (int i = tid; i < wn; i += 256) {
        float ex = __expf(attn_out[lo + w0 + i]);
        sex[i] = ex;
        ssrc[i] = src_idx[lo + w0 + i];
        attn_out[lo + w0 + i] = ex * inv;
      }
      const int padw = (wn + 7) & ~7;
      for (int i = wn + tid; i < padw; i += 256) { sex[i] = 0.f; ssrc[i] = 0; }
      __syncthreads();
      const int nb = (wn + 7) >> 3;
      for (int b = wv; b < nb; b += 4) {
        const int base = b * 8;
#pragma unroll
        for (int j = 0; j < 8; j++) {
          float ex = sex[base + j];
          int s = ssrc[base + j];
          uint32 u = h_src_bf2[(size_t)s * 64 + t2];
          accx = fmaf(ex, bf_lo(u), accx);
          accy = fmaf(ex, bf_hi(u), accy);
        }
      }
    }
  }

  // cross-wave reduce + bf16 h_global store
  sacc[wv][t2 * 2] = accx;
  sacc[wv][t2 * 2 + 1] = accy;
  __syncthreads();
  if (tid < 64) {
    float sx = (sacc[0][tid * 2] + sacc[1][tid * 2]) + (sacc[2][tid * 2] + sacc[3][tid * 2]);
    float sy = (sacc[0][tid * 2 + 1] + sacc[1][tid * 2 + 1]) +
               (sacc[2][tid * 2 + 1] + sacc[3][tid * 2 + 1]);
    h_glob_bf[(size_t)v * 64 + tid] = pack_bf2(sx * inv, sy * inv);
  }
}

// ---------------------------------------------------------------------------
// MFMA output projection + fused LayerNorm.
// out = [h_dst|h_glob](bf16) @ Wo_frag + bo; x = h_dst(f32) + out; y = LN(x).
// 128 threads = 2 waves x 16 rows -> 32 rows/block.
// Row sum: 8-reg in-lane add + 4-step shfl over m (stays within quad).
// ---------------------------------------------------------------------------
__global__ __launch_bounds__(128) void out_mfma_ln(
    const ushort_t* __restrict__ h_dst_bf, const ushort_t* __restrict__ h_glob_bf,
    const ushort_t* __restrict__ Wo_frag,
    const float* __restrict__ h_dst, const float* __restrict__ bo,
    const float* __restrict__ gamma, const float* __restrict__ beta,
    float* __restrict__ y, int N) {
  __shared__ float sbo[128], sgam[128], sbet[128];
  const int tid = threadIdx.x;
  if (tid < 128) { sbo[tid] = bo[tid]; sgam[tid] = gamma[tid]; sbet[tid] = beta[tid]; }
  __syncthreads();

  const int w = tid >> 6;
  const int lane = tid & 63;
  const int m = lane & 15;
  const int quad = lane >> 4;
  const int row0 = blockIdx.x * 32 + w * 16;
  const int ra = min(row0 + m, N - 1);
  const bf16x8* Wf = (const bf16x8*)Wo_frag;

  f32x4 acc[8];
#pragma unroll
  for (int nt = 0; nt < 8; nt++) acc[nt] = (f32x4){0.f, 0.f, 0.f, 0.f};

#pragma unroll
  for (int kc = 0; kc < 8; kc++) {
    const ushort_t* X = (kc < 4) ? h_dst_bf : h_glob_bf;
    const int kk = kc & 3;
    bf16x8 a = *(const bf16x8*)(X + (size_t)ra * D128 + kk * 32 + quad * 8);
#pragma unroll
    for (int nt = 0; nt < 8; nt++) {
      bf16x8 bfr = Wf[(nt * 8 + kc) * 64 + lane];
      acc[nt] = __builtin_amdgcn_mfma_f32_16x16x32_bf16(a, bfr, acc[nt], 0, 0, 0);
    }
  }

  // epilogue: per r, row = row0 + quad*4 + r held across 16 lanes (m) x 8 regs
#pragma unroll
  for (int r = 0; r < 4; r++) {
    const int grow = row0 + quad * 4 + r;
    const int gr = min(grow, N - 1);
    float x[8];
    float s1 = 0.f, s2 = 0.f;
#pragma unroll
    for (int nt = 0; nt < 8; nt++) {
      float hd = h_dst[(size_t)gr * D128 + nt * 16 + m];
      float xv = hd + acc[nt][r] + sbo[nt * 16 + m];
      x[nt] = xv;
      s1 += xv;
      s2 = fmaf(xv, xv, s2);
    }
#pragma unroll
    for (int o = 1; o <= 8; o <<= 1) {
      s1 += __shfl_xor(s1, o, 64);
      s2 += __shfl_xor(s2, o, 64);
    }
    float mu = s1 * (1.0f / 128.0f);
    float var = s2 * (1.0f / 128.0f) - mu * mu;
    float rstd = __builtin_amdgcn_rcpf(sqrtf(var + 1e-5f));
    if (grow < N) {
#pragma unroll
      for (int nt = 0; nt < 8; nt++) {
        int c = nt * 16 + m;
        y[(size_t)grow * D128 + c] = (x[nt] - mu) * rstd * sgam[c] + sbet[c];
      }
    }
  }
}

extern "C" void kernel_launch(void* const* d_in, const int* in_sizes, int n_in,
                              void* d_out, int out_size, void* d_ws, size_t ws_size,
                              hipStream_t stream) {
  const float* h_src = (const float*)d_in[0];
  const float* h_dst = (const float*)d_in[1];
  const float* s_emb = (const float*)d_in[2];
  const float* ew    = (const float*)d_in[3];
  const int* src_idx = (const int*)d_in[4];
  const int* dst_idx = (const int*)d_in[5];
  const float* W1    = (const float*)d_in[6];
  const float* w2    = (const float*)d_in[7];
  const float* Wo    = (const float*)d_in[8];
  const float* bo    = (const float*)d_in[9];
  const float* gamma = (const float*)d_in[10];
  const float* beta  = (const float*)d_in[11];

  const int N_src = in_sizes[0] / D128;
  const int N_dst = in_sizes[1] / D128;
  const int E = in_sizes[3];

  float* out_y = (float*)d_out;                       // [N_dst*128]
  float* out_attn = out_y + (size_t)N_dst * D128;     // [E]

  // ws layout (uints hold 2 bf16):
  uint32* p_src_bf = (uint32*)d_ws;                            // N_src*64
  uint32* p_dst_bf = p_src_bf + (size_t)N_src * 64;            // N_dst*64
  uint32* h_src_bf = p_dst_bf + (size_t)N_dst * 64;            // N_src*64
  uint32* h_dst_bf = h_src_bf + (size_t)N_src * 64;            // N_dst*64
  uint32* h_glob_bf = h_dst_bf + (size_t)N_dst * 64;           // N_dst*64
  uint32* s_emb_bf = h_glob_bf + (size_t)N_dst * 64;           // N_dst*64
  int* seg_off = (int*)(s_emb_bf + (size_t)N_dst * 64);        // N_dst+1
  ushort_t* Wfrag = (ushort_t*)(seg_off + N_dst + 1 + 3);      // 32768 shorts
  ushort_t* Wo_frag = Wfrag + 32768;                           // 32768 shorts

  const int n_src_el = N_src * D128;
  const int n_dst_el = N_dst * D128;
  const int n_tot_el = n_src_el + 2 * n_dst_el;
  const int nblk_a = (N_src + 127) / 128;
  const int nblk_b = (N_dst + 127) / 128;
  const int nb_conv = (n_tot_el / 8 + 255) / 256;
  const int nb_seg = (E + 255) / 256;

  prep_all<<<nb_conv + 32 + nb_seg, 256, 0, stream>>>(
      h_src, s_emb, h_dst, W1, Wo, dst_idx,
      h_src_bf, s_emb_bf, h_dst_bf, Wfrag, Wo_frag, seg_off,
      n_src_el, n_dst_el, E, N_dst, nb_conv);
  gemm_mfma<<<nblk_a + nblk_b, 256, 0, stream>>>(
      (const ushort_t*)h_src_bf, (const ushort_t*)s_emb_bf, Wfrag,
      (ushort_t*)p_src_bf, (ushort_t*)p_dst_bf, N_src, N_dst, nblk_a);
  attn_agg_kernel<<<N_dst, 256, 0, stream>>>(
      p_src_bf, p_dst_bf, w2, ew, src_idx, seg_off, h_src_bf, out_attn, h_glob_bf);
  out_mfma_ln<<<(N_dst + 31) / 32, 128, 0, stream>>>(
      (const ushort_t*)h_dst_bf, (const ushort_t*)h_glob_bf, Wo_frag,
      h_dst, bo, gamma, beta, out_y, N_dst);
}

// Round 10
// 176.414 us; speedup vs baseline: 1.2054x; 1.0053x over previous
//
#include <hip/hip_runtime.h>
#include <math.h>

#define D128 128
#define SCAPW 256   // per-wave LDS score capacity (deg ~ Poisson(32); P(deg>256)~0)

typedef unsigned int uint32;
typedef unsigned short ushort_t;
typedef short bf16x8 __attribute__((ext_vector_type(8)));
typedef float f32x4 __attribute__((ext_vector_type(4)));

// fp32 -> bf16 (RNE)
__device__ __forceinline__ ushort_t bf16_of(float x) {
  uint32 u = __float_as_uint(x);
  return (ushort_t)((u + 0x7fffu + ((u >> 16) & 1u)) >> 16);
}
__device__ __forceinline__ uint32 pack_bf2(float x, float y) {
  uint32 bx = __float_as_uint(x);
  uint32 by = __float_as_uint(y);
  bx = (bx + 0x7fffu + ((bx >> 16) & 1u)) >> 16;
  by = (by + 0x7fffu + ((by >> 16) & 1u)) & 0xffff0000u;
  return bx | by;
}
__device__ __forceinline__ float bf_lo(uint32 u) { return __uint_as_float(u << 16); }
__device__ __forceinline__ float bf_hi(uint32 u) { return __uint_as_float(u & 0xffff0000u); }

// tanh(x) = 1 - 2/(1+exp(2x)) via v_exp + v_rcp
__device__ __forceinline__ float fast_tanh(float x) {
  float e = __expf(2.0f * x);
  float r = __builtin_amdgcn_rcpf(1.0f + e);
  return fmaf(-2.0f, r, 1.0f);
}

// ---------------------------------------------------------------------------
// prep_all: one dispatch, block-range partitioned:
//   [0, nb_conv)       : fp32->bf16 convert of h_src, s_emb, h_dst (streaming)
//   [nb_conv, +16)     : W1 -> MFMA-fragment-ordered bf16 Wfrag (K=128 x2)
//   [+16, +16)         : Wo -> MFMA-fragment-ordered bf16 Wo_frag (K=256)
//   [+32, ...)         : segment offsets from sorted dst_idx
// ---------------------------------------------------------------------------
__global__ __launch_bounds__(256) void prep_all(
    const float* __restrict__ h_src, const float* __restrict__ s_emb,
    const float* __restrict__ h_dst,
    const float* __restrict__ W1, const float* __restrict__ Wo,
    const int* __restrict__ dst_idx,
    uint32* __restrict__ h_src_bf, uint32* __restrict__ s_emb_bf,
    uint32* __restrict__ h_dst_bf,
    ushort_t* __restrict__ Wfrag, ushort_t* __restrict__ Wo_frag,
    int* __restrict__ off,
    int n_src_el, int n_dst_el, int E, int N, int nb_conv) {
  const int b = blockIdx.x;
  const int tid = threadIdx.x;
  if (b < nb_conv) {
    int i = (b * 256 + tid) * 8;
    const int n_tot_el = n_src_el + 2 * n_dst_el;
    if (i >= n_tot_el) return;
    const float* src;
    uint32* dst;
    if (i < n_src_el) { src = h_src + i; dst = h_src_bf + (i >> 1); }
    else if (i < n_src_el + n_dst_el) {
      src = s_emb + (i - n_src_el); dst = s_emb_bf + ((i - n_src_el) >> 1);
    } else {
      src = h_dst + (i - n_src_el - n_dst_el);
      dst = h_dst_bf + ((i - n_src_el - n_dst_el) >> 1);
    }
    float4 a = *(const float4*)src;
    float4 c = *(const float4*)(src + 4);
    uint4 p;
    p.x = pack_bf2(a.x, a.y);
    p.y = pack_bf2(a.z, a.w);
    p.z = pack_bf2(c.x, c.y);
    p.w = pack_bf2(c.z, c.w);
    *(uint4*)dst = p;
  } else if (b < nb_conv + 16) {
    // W1 fragments: t indexes [h][nt][kc][lane]
    int t = (b - nb_conv) * 256 + tid;   // 0..4095
    int lane = t & 63;
    int kc = (t >> 6) & 3;
    int nt = (t >> 8) & 7;
    int h = (t >> 11) & 1;
    int m = lane & 15;
    int quad = lane >> 4;
    int krow = h * D128 + kc * 32 + quad * 8;
    int ncol = nt * 16 + m;
    ushort_t fr[8];
#pragma unroll
    for (int j = 0; j < 8; j++) fr[j] = bf16_of(W1[(size_t)(krow + j) * D128 + ncol]);
    *(uint4*)(Wfrag + (size_t)t * 8) = *(const uint4*)fr;
  } else if (b < nb_conv + 32) {
    // Wo fragments: t indexes [nt][kc8][lane], kc8 in 0..7 (K=256)
    int t = (b - nb_conv - 16) * 256 + tid;   // 0..4095
    int lane = t & 63;
    int kc = (t >> 6) & 7;
    int nt = (t >> 9) & 7;
    int m = lane & 15;
    int quad = lane >> 4;
    int krow = kc * 32 + quad * 8;
    int ncol = nt * 16 + m;
    ushort_t fr[8];
#pragma unroll
    for (int j = 0; j < 8; j++) fr[j] = bf16_of(Wo[(size_t)(krow + j) * D128 + ncol]);
    *(uint4*)(Wo_frag + (size_t)t * 8) = *(const uint4*)fr;
  } else {
    int e = (b - nb_conv - 32) * 256 + tid;
    if (e >= E) return;
    int d = dst_idx[e];
    int dprev = (e == 0) ? -1 : dst_idx[e - 1];
    for (int v = dprev + 1; v <= d; v++) off[v] = e;
    if (e == E - 1) {
      for (int v = d + 1; v <= N; v++) off[v] = E;
    }
  }
}

// ---------------------------------------------------------------------------
// Merged GEMM: P = X @ W for two problems in one dispatch (bf16 MFMA).
// A: direct per-lane global loads. B: fragment-ordered Wfrag (1 KB wave-loads,
// L2-hot). Epilogue: LDS repack -> coalesced 8-B stores.
// ---------------------------------------------------------------------------
__global__ __launch_bounds__(256) void gemm_mfma(
    const ushort_t* __restrict__ Xa, const ushort_t* __restrict__ Xb,
    const ushort_t* __restrict__ Wfrag,
    ushort_t* __restrict__ Pa, ushort_t* __restrict__ Pb,
    int Ma, int Mb, int nblk_a) {
  __shared__ ushort_t Ys[128][132];
  const int blk = blockIdx.x;
  const ushort_t* X;
  const bf16x8* Wf;
  ushort_t* P;
  int M, row0;
  if (blk < nblk_a) { X = Xa; P = Pa; Wf = (const bf16x8*)Wfrag;           M = Ma; row0 = blk * 128; }
  else              { X = Xb; P = Pb; Wf = (const bf16x8*)(Wfrag + 16384); M = Mb; row0 = (blk - nblk_a) * 128; }

  const int tid = threadIdx.x;
  const int wave = tid >> 6;
  const int lane = tid & 63;
  const int m = lane & 15;
  const int quad = lane >> 4;

  const int ra0 = min(row0 + wave * 32 + m, M - 1);
  const int ra1 = min(row0 + wave * 32 + 16 + m, M - 1);

  f32x4 acc[2][8];
#pragma unroll
  for (int st = 0; st < 2; st++)
#pragma unroll
    for (int nt = 0; nt < 8; nt++) acc[st][nt] = (f32x4){0.f, 0.f, 0.f, 0.f};

#pragma unroll
  for (int kc = 0; kc < 4; kc++) {
    bf16x8 a0 = *(const bf16x8*)(X + (size_t)ra0 * D128 + kc * 32 + quad * 8);
    bf16x8 a1 = *(const bf16x8*)(X + (size_t)ra1 * D128 + kc * 32 + quad * 8);
#pragma unroll
    for (int nt = 0; nt < 8; nt++) {
      bf16x8 bfr = Wf[(nt * 4 + kc) * 64 + lane];
      acc[0][nt] = __builtin_amdgcn_mfma_f32_16x16x32_bf16(a0, bfr, acc[0][nt], 0, 0, 0);
      acc[1][nt] = __builtin_amdgcn_mfma_f32_16x16x32_bf16(a1, bfr, acc[1][nt], 0, 0, 0);
    }
  }

#pragma unroll
  for (int st = 0; st < 2; st++)
#pragma unroll
    for (int nt = 0; nt < 8; nt++)
#pragma unroll
      for (int r = 0; r < 4; r++)
        Ys[wave * 32 + st * 16 + quad * 4 + r][nt * 16 + m] = bf16_of(acc[st][nt][r]);
  __syncthreads();

#pragma unroll
  for (int it = 0; it < 16; it++) {
    int f = tid + 256 * it;
    int row = f >> 5;
    int c = (f & 31) * 4;
    int grow = row0 + row;
    if (grow < M) {
      uint2 v = *(const uint2*)(&Ys[row][c]);
      *(uint2*)(P + (size_t)grow * D128 + c) = v;
    }
  }
}

// ---------------------------------------------------------------------------
// Fused attention + aggregation, WAVE-PER-DST (4 dst per 256-thread block).
// No block barriers after w2 staging; all reductions in-wave.
// Score phase: 16 lanes/edge, ex=exp(score) computed inline, den in registers.
// Agg phase: 64 lanes = 2 channels/lane, 8 row-gathers in flight.
// deg > SCAPW: wave-level slow path staged via attn_out global (P ~ 0).
// ---------------------------------------------------------------------------
__global__ __launch_bounds__(256) void attn_agg_kernel(
    const uint32* __restrict__ p_src_bf, const uint32* __restrict__ p_dst_bf,
    const float* __restrict__ w2, const float* __restrict__ ew,
    const int* __restrict__ src_idx, const int* __restrict__ off,
    const uint32* __restrict__ h_src_bf2,
    float* __restrict__ attn_out, uint32* __restrict__ h_glob_bf, int N_dst) {
  const int tid = threadIdx.x;
  const int wv = tid >> 6;
  const int lane = tid & 63;
  const int v = blockIdx.x * 4 + wv;

  __shared__ float sw2[128];
  __shared__ float sex[4][SCAPW];
  __shared__ int ssrc[4][SCAPW];

  if (tid < 128) sw2[tid] = w2[tid];
  __syncthreads();
  if (v >= N_dst) return;

  const int lo = off[v], hi = off[v + 1];
  const int deg = hi - lo;
  const int sub = lane & 15;   // lane within edge -> channels sub*8..+7
  const int eg = lane >> 4;    // edge slot 0..3 within wave

  // per-lane p_dst segment + w2 segment (wave-uniform row, L1-hot)
  uint4 ud = *(const uint4*)(p_dst_bf + (size_t)v * 64 + sub * 4);
  float4 wA = *(const float4*)(&sw2[sub * 8]);
  float4 wB = *(const float4*)(&sw2[sub * 8 + 4]);

  float den = 0.f;
  float accx = 0.f, accy = 0.f;

  if (deg <= SCAPW) {
    // ---- fast path ----
    for (int base = 0; base < deg; base += 4) {
      const int ei = base + eg;
      float acc = 0.f, ewv = 0.f;
      int s = 0;
      if (ei < deg) {
        const int e = lo + ei;
        s = src_idx[e];
        ewv = ew[e];
        uint4 us = *(const uint4*)(p_src_bf + (size_t)s * 64 + sub * 4);
        acc = fast_tanh(bf_lo(us.x) + bf_lo(ud.x)) * wA.x;
        acc = fmaf(fast_tanh(bf_hi(us.x) + bf_hi(ud.x)), wA.y, acc);
        acc = fmaf(fast_tanh(bf_lo(us.y) + bf_lo(ud.y)), wA.z, acc);
        acc = fmaf(fast_tanh(bf_hi(us.y) + bf_hi(ud.y)), wA.w, acc);
        acc = fmaf(fast_tanh(bf_lo(us.z) + bf_lo(ud.z)), wB.x, acc);
        acc = fmaf(fast_tanh(bf_hi(us.z) + bf_hi(ud.z)), wB.y, acc);
        acc = fmaf(fast_tanh(bf_lo(us.w) + bf_lo(ud.w)), wB.z, acc);
        acc = fmaf(fast_tanh(bf_hi(us.w) + bf_hi(ud.w)), wB.w, acc);
      }
#pragma unroll
      for (int o = 1; o <= 8; o <<= 1) acc += __shfl_xor(acc, o, 64);
      float ex = 0.f;
      if (ei < deg) {
        ex = __expf(acc * ewv);
        if (sub == 0) { sex[wv][ei] = ex; ssrc[wv][ei] = s; }
      }
      den += (sub == 0) ? ex : 0.f;
    }
    // pad to multiple of 8 (ex=0 contributes nothing)
    const int pad = (deg + 7) & ~7;
    for (int i = deg + lane; i < pad; i += 64) { sex[wv][i] = 0.f; ssrc[wv][i] = 0; }
    // wave-reduce den
#pragma unroll
    for (int o = 1; o <= 32; o <<= 1) den += __shfl_xor(den, o, 64);
    const float inv = (deg > 0) ? 1.0f / den : 0.0f;

    // contiguous normalized attn store
    for (int i = lane; i < deg; i += 64) attn_out[lo + i] = sex[wv][i] * inv;

    // aggregation: 8 row-gathers in flight
    const int nb = pad >> 3;
    for (int b = 0; b < nb; b++) {
      const int base = b * 8;
#pragma unroll
      for (int j = 0; j < 8; j++) {
        float ex = sex[wv][base + j];
        int s = ssrc[wv][base + j];
        uint32 u = h_src_bf2[(size_t)s * 64 + lane];
        accx = fmaf(ex, bf_lo(u), accx);
        accy = fmaf(ex, bf_hi(u), accy);
      }
    }
    h_glob_bf[(size_t)v * 64 + lane] = pack_bf2(accx * inv, accy * inv);
  } else {
    // ---- slow path (deg > SCAPW): stage ex via attn_out global ----
    for (int base = 0; base < deg; base += 4) {
      const int ei = base + eg;
      float acc = 0.f, ewv = 0.f;
      if (ei < deg) {
        const int e = lo + ei;
        int s = src_idx[e];
        ewv = ew[e];
        uint4 us = *(const uint4*)(p_src_bf + (size_t)s * 64 + sub * 4);
        acc = fast_tanh(bf_lo(us.x) + bf_lo(ud.x)) * wA.x;
        acc = fmaf(fast_tanh(bf_hi(us.x) + bf_hi(ud.x)), wA.y, acc);
        acc = fmaf(fast_tanh(bf_lo(us.y) + bf_lo(ud.y)), wA.z, acc);
        acc = fmaf(fast_tanh(bf_hi(us.y) + bf_hi(ud.y)), wA.w, acc);
        acc = fmaf(fast_tanh(bf_lo(us.z) + bf_lo(ud.z)), wB.x, acc);
        acc = fmaf(fast_tanh(bf_hi(us.z) + bf_hi(ud.z)), wB.y, acc);
        acc = fmaf(fast_tanh(bf_lo(us.w) + bf_lo(ud.w)), wB.z, acc);
        acc = fmaf(fast_tanh(bf_hi(us.w) + bf_hi(ud.w)), wB.w, acc);
      }
#pragma unroll
      for (int o = 1; o <= 8; o <<= 1) acc += __shfl_xor(acc, o, 64);
      float ex = 0.f;
      if (ei < deg) {
        ex = __expf(acc * ewv);
        if (sub == 0) attn_out[lo + ei] = ex;
      }
      den += (sub == 0) ? ex : 0.f;
    }
#pragma unroll
    for (int o = 1; o <= 32; o <<= 1) den += __shfl_xor(den, o, 64);
    const float inv = 1.0f / den;

    for (int i0 = 0; i0 < deg; i0 += 8) {
#pragma unroll
      for (int j = 0; j < 8; j++) {
        const int i = i0 + j;
        float ex = 0.f;
        int s = 0;
        if (i < deg) { ex = attn_out[lo + i]; s = src_idx[lo + i]; }
        uint32 u = h_src_bf2[(size_t)s * 64 + lane];
        accx = fmaf(ex, bf_lo(u), accx);
        accy = fmaf(ex, bf_hi(u), accy);
        if (i < deg && lane == 0) attn_out[lo + i] = ex * inv;  // after read
      }
    }
    h_glob_bf[(size_t)v * 64 + lane] = pack_bf2(accx * inv, accy * inv);
  }
}

// ---------------------------------------------------------------------------
// MFMA output projection + fused LayerNorm.
// out = [h_dst|h_glob](bf16) @ Wo_frag + bo; x = h_dst(f32) + out; y = LN(x).
// 128 threads = 2 waves x 16 rows -> 32 rows/block.
// ---------------------------------------------------------------------------
__global__ __launch_bounds__(128) void out_mfma_ln(
    const ushort_t* __restrict__ h_dst_bf, const ushort_t* __restrict__ h_glob_bf,
    const ushort_t* __restrict__ Wo_frag,
    const float* __restrict__ h_dst, const float* __restrict__ bo,
    const float* __restrict__ gamma, const float* __restrict__ beta,
    float* __restrict__ y, int N) {
  __shared__ float sbo[128], sgam[128], sbet[128];
  const int tid = threadIdx.x;
  if (tid < 128) { sbo[tid] = bo[tid]; sgam[tid] = gamma[tid]; sbet[tid] = beta[tid]; }
  __syncthreads();

  const int w = tid >> 6;
  const int lane = tid & 63;
  const int m = lane & 15;
  const int quad = lane >> 4;
  const int row0 = blockIdx.x * 32 + w * 16;
  const int ra = min(row0 + m, N - 1);
  const bf16x8* Wf = (const bf16x8*)Wo_frag;

  f32x4 acc[8];
#pragma unroll
  for (int nt = 0; nt < 8; nt++) acc[nt] = (f32x4){0.f, 0.f, 0.f, 0.f};

#pragma unroll
  for (int kc = 0; kc < 8; kc++) {
    const ushort_t* X = (kc < 4) ? h_dst_bf : h_glob_bf;
    const int kk = kc & 3;
    bf16x8 a = *(const bf16x8*)(X + (size_t)ra * D128 + kk * 32 + quad * 8);
#pragma unroll
    for (int nt = 0; nt < 8; nt++) {
      bf16x8 bfr = Wf[(nt * 8 + kc) * 64 + lane];
      acc[nt] = __builtin_amdgcn_mfma_f32_16x16x32_bf16(a, bfr, acc[nt], 0, 0, 0);
    }
  }

#pragma unroll
  for (int r = 0; r < 4; r++) {
    const int grow = row0 + quad * 4 + r;
    const int gr = min(grow, N - 1);
    float x[8];
    float s1 = 0.f, s2 = 0.f;
#pragma unroll
    for (int nt = 0; nt < 8; nt++) {
      float hd = h_dst[(size_t)gr * D128 + nt * 16 + m];
      float xv = hd + acc[nt][r] + sbo[nt * 16 + m];
      x[nt] = xv;
      s1 += xv;
      s2 = fmaf(xv, xv, s2);
    }
#pragma unroll
    for (int o = 1; o <= 8; o <<= 1) {
      s1 += __shfl_xor(s1, o, 64);
      s2 += __shfl_xor(s2, o, 64);
    }
    float mu = s1 * (1.0f / 128.0f);
    float var = s2 * (1.0f / 128.0f) - mu * mu;
    float rstd = __builtin_amdgcn_rcpf(sqrtf(var + 1e-5f));
    if (grow < N) {
#pragma unroll
      for (int nt = 0; nt < 8; nt++) {
        int c = nt * 16 + m;
        y[(size_t)grow * D128 + c] = (x[nt] - mu) * rstd * sgam[c] + sbet[c];
      }
    }
  }
}

extern "C" void kernel_launch(void* const* d_in, const int* in_sizes, int n_in,
                              void* d_out, int out_size, void* d_ws, size_t ws_size,
                              hipStream_t stream) {
  const float* h_src = (const float*)d_in[0];
  const float* h_dst = (const float*)d_in[1];
  const float* s_emb = (const float*)d_in[2];
  const float* ew    = (const float*)d_in[3];
  const int* src_idx = (const int*)d_in[4];
  const int* dst_idx = (const int*)d_in[5];
  const float* W1    = (const float*)d_in[6];
  const float* w2    = (const float*)d_in[7];
  const float* Wo    = (const float*)d_in[8];
  const float* bo    = (const float*)d_in[9];
  const float* gamma = (const float*)d_in[10];
  const float* beta  = (const float*)d_in[11];

  const int N_src = in_sizes[0] / D128;
  const int N_dst = in_sizes[1] / D128;
  const int E = in_sizes[3];

  float* out_y = (float*)d_out;                       // [N_dst*128]
  float* out_attn = out_y + (size_t)N_dst * D128;     // [E]

  // ws layout (uints hold 2 bf16):
  uint32* p_src_bf = (uint32*)d_ws;                            // N_src*64
  uint32* p_dst_bf = p_src_bf + (size_t)N_src * 64;            // N_dst*64
  uint32* h_src_bf = p_dst_bf + (size_t)N_dst * 64;            // N_src*64
  uint32* h_dst_bf = h_src_bf + (size_t)N_src * 64;            // N_dst*64
  uint32* h_glob_bf = h_dst_bf + (size_t)N_dst * 64;           // N_dst*64
  uint32* s_emb_bf = h_glob_bf + (size_t)N_dst * 64;           // N_dst*64
  int* seg_off = (int*)(s_emb_bf + (size_t)N_dst * 64);        // N_dst+1
  ushort_t* Wfrag = (ushort_t*)(seg_off + N_dst + 1 + 3);      // 32768 shorts
  ushort_t* Wo_frag = Wfrag + 32768;                           // 32768 shorts

  const int n_src_el = N_src * D128;
  const int n_dst_el = N_dst * D128;
  const int n_tot_el = n_src_el + 2 * n_dst_el;
  const int nblk_a = (N_src + 127) / 128;
  const int nblk_b = (N_dst + 127) / 128;
  const int nb_conv = (n_tot_el / 8 + 255) / 256;
  const int nb_seg = (E + 255) / 256;

  prep_all<<<nb_conv + 32 + nb_seg, 256, 0, stream>>>(
      h_src, s_emb, h_dst, W1, Wo, dst_idx,
      h_src_bf, s_emb_bf, h_dst_bf, Wfrag, Wo_frag, seg_off,
      n_src_el, n_dst_el, E, N_dst, nb_conv);
  gemm_mfma<<<nblk_a + nblk_b, 256, 0, stream>>>(
      (const ushort_t*)h_src_bf, (const ushort_t*)s_emb_bf, Wfrag,
      (ushort_t*)p_src_bf, (ushort_t*)p_dst_bf, N_src, N_dst, nblk_a);
  attn_agg_kernel<<<(N_dst + 3) / 4, 256, 0, stream>>>(
      p_src_bf, p_dst_bf, w2, ew, src_idx, seg_off, h_src_bf, out_attn,
      h_glob_bf, N_dst);
  out_mfma_ln<<<(N_dst + 31) / 32, 128, 0, stream>>>(
      (const ushort_t*)h_dst_bf, (const ushort_t*)h_glob_bf, Wo_frag,
      h_dst, bo, gamma, beta, out_y, N_dst);
}